// Round 1
// baseline (8888.190 us; speedup 1.0000x reference)
//
#include <hip/hip_runtime.h>
#include <hip/hip_bf16.h>
#include <stdint.h>

// Problem constants
#define TT 256
#define BB 64
#define AA 512
#define II 1024
#define HH 1024
#define LL 2
// derived
#define BH 65536        // B*H
#define B4H 262144      // B*4H
#define OUT_HS 16777216 // T*B*H
#define OUT_HL 16777216
#define OUT_CL (16777216 + 131072)

typedef __attribute__((ext_vector_type(8))) short bf16x8;
typedef __attribute__((ext_vector_type(4))) float f32x4;

__device__ __forceinline__ ushort f2bf(float v) {
    union { float f; uint32_t u; } x; x.f = v;
    uint32_t r = x.u + 0x7fff + ((x.u >> 16) & 1);
    return (ushort)(r >> 16);
}

// Build Wt[l][col'][k] bf16, col' = u*4+g for source column col=g*1024+u,
// k in [0,1024) from W_ih[k][col], k in [1024,2048) from W_hh[k-1024][col].
__global__ __launch_bounds__(256) void k_prep_wt(const float* __restrict__ wih,
                                                 const float* __restrict__ whh,
                                                 ushort* __restrict__ Wt) {
    __shared__ ushort tile[64][65];
    const int l = blockIdx.z;
    const int k0 = blockIdx.x * 64;    // 0..2047
    const int col0 = blockIdx.y * 64;  // 0..4095
    const int tid = threadIdx.x;
    const int cl = tid & 63, ks = tid >> 6;
    const float* src;
    int krow0;
    if (k0 < 1024) { src = wih + (size_t)l * 1024 * 4096; krow0 = k0; }
    else           { src = whh + (size_t)l * 1024 * 4096; krow0 = k0 - 1024; }
#pragma unroll
    for (int i = 0; i < 16; ++i) {
        int kl = ks + i * 4;
        tile[kl][cl] = f2bf(src[(size_t)(krow0 + kl) * 4096 + col0 + cl]);
    }
    __syncthreads();
    const int g0 = col0 >> 10, ub = col0 & 1023;
    ushort* dst = Wt + (size_t)l * 4096 * 2048;
    const int klane = tid & 63;
#pragma unroll
    for (int i = 0; i < 16; ++i) {
        int cl2 = (tid >> 6) + i * 4;
        int row = (ub + cl2) * 4 + g0;
        dst[(size_t)row * 2048 + k0 + klane] = tile[klane][cl2];
    }
}

__global__ __launch_bounds__(256) void k_cast_x(const float* __restrict__ x,
                                                ushort* __restrict__ xbf) {
    int i = blockIdx.x * 256 + threadIdx.x; // 4,194,304 threads, 4 elems each
    const float4* xv = (const float4*)x;
    float4 v = xv[i];
    ushort4 o;
    o.x = f2bf(v.x); o.y = f2bf(v.y); o.z = f2bf(v.z); o.w = f2bf(v.w);
    ((ushort4*)xbf)[i] = o;
}

// const[l][b][col] = a0[b,:] @ W_ah[l][:,col] + bias_ah + bias_ih + bias_hh
__global__ __launch_bounds__(256) void k_const(const float* __restrict__ attn,
                                               const float* __restrict__ wah,
                                               const float* __restrict__ bah,
                                               const float* __restrict__ bih,
                                               const float* __restrict__ bhh,
                                               float* __restrict__ constg) {
    const int tid = threadIdx.x;
    const int col = blockIdx.x * 256 + tid;
    const int b0 = blockIdx.y * 8;
    const int l = blockIdx.z;
    const float* W = wah + (size_t)l * 512 * 4096;
    float acc[8] = {0.f, 0.f, 0.f, 0.f, 0.f, 0.f, 0.f, 0.f};
    for (int k = 0; k < 512; ++k) {
        float wv = W[(size_t)k * 4096 + col];
#pragma unroll
        for (int j = 0; j < 8; ++j) acc[j] += attn[(b0 + j) * 512 + k] * wv;
    }
    float bias = bah[l * 4096 + col] + bih[l * 4096 + col] + bhh[l * 4096 + col];
    float* cg = constg + (size_t)l * B4H;
#pragma unroll
    for (int j = 0; j < 8; ++j) cg[(size_t)(b0 + j) * 4096 + col] = acc[j] + bias;
}

__global__ __launch_bounds__(256) void k_init(const float* __restrict__ h0,
                                              const float* __restrict__ c0,
                                              ushort* __restrict__ hs0,
                                              ushort* __restrict__ h1,
                                              float* __restrict__ cst) {
    int i = blockIdx.x * 256 + threadIdx.x; // 0..131071  ([L][B][H])
    float h = h0[i];
    cst[i] = c0[i];
    if (i < BH) hs0[i] = f2bf(h);          // layer0 slot 0
    else        h1[i - BH] = f2bf(h);      // layer1 ping-pong slot 0
}

// One pipelined step: layer0 does t=s (s<256), layer1 does t=s-1 (s>=1).
// 256 blocks x 512 threads. Block owns 4 hidden units (16 gate cols) per layer.
// Waves 0-3: layer0 rows 16w..16w+15; waves 4-7: layer1.
__global__ __launch_bounds__(512) void k_step(const ushort* __restrict__ xbf,
                                              ushort* __restrict__ hs0,
                                              ushort* __restrict__ h1,
                                              const ushort* __restrict__ Wt,
                                              const float* __restrict__ constg,
                                              float* __restrict__ cst,
                                              float* __restrict__ out, int s) {
    __shared__ float lds[8][16][17];
    const int tid = threadIdx.x;
    const int w = tid >> 6, lane = tid & 63;
    const int layer = w >> 2, wm = w & 3;
    const int u0 = blockIdx.x * 4;

    int t, active;
    const ushort *Ax, *Ah;
    const float* cg;
    float* cs;
    if (layer == 0) {
        active = (s < TT); t = s;
        Ax = xbf + (size_t)t * BH;
        Ah = hs0 + (size_t)s * BH;
        cg = constg; cs = cst;
    } else {
        active = (s >= 1); t = s - 1;
        Ax = hs0 + (size_t)s * BH;          // layer0 h_t, written previous launch
        Ah = h1 + (size_t)(t & 1) * BH;
        cg = constg + B4H; cs = cst + BH;
    }

    if (active) {
        f32x4 acc = {0.f, 0.f, 0.f, 0.f};
        const int bf = wm * 16 + (lane & 15);   // A-fragment row (batch)
        const int koff = (lane >> 4) * 8;       // A/B fragment k offset
        const ushort* Bl = Wt + ((size_t)layer * 4096 + (size_t)(u0 * 4 + (lane & 15))) * 2048 + koff;
        const ushort* Axl = Ax + (size_t)bf * 1024 + koff;
        const ushort* Ahl = Ah + (size_t)bf * 1024 + koff;
#pragma unroll 4
        for (int kt = 0; kt < 32; ++kt) {
            bf16x8 a = *(const bf16x8*)(Axl + kt * 32);
            bf16x8 b = *(const bf16x8*)(Bl + kt * 32);
            acc = __builtin_amdgcn_mfma_f32_16x16x32_bf16(a, b, acc, 0, 0, 0);
        }
#pragma unroll 4
        for (int kt = 0; kt < 32; ++kt) {
            bf16x8 a = *(const bf16x8*)(Ahl + kt * 32);
            bf16x8 b = *(const bf16x8*)(Bl + 1024 + kt * 32);
            acc = __builtin_amdgcn_mfma_f32_16x16x32_bf16(a, b, acc, 0, 0, 0);
        }
        // C/D layout: col = lane&15, row = (lane>>4)*4 + r   [m89-verified]
        const int c = lane & 15;
        const int u = u0 + (c >> 2), g = c & 3, col = (g << 10) + u;
        const int r0 = (lane >> 4) * 4;
#pragma unroll
        for (int r = 0; r < 4; ++r) {
            int b = wm * 16 + r0 + r;
            lds[w][r0 + r][c] = acc[r] + cg[(size_t)b * 4096 + col];
        }
    }
    __syncthreads();
    if (active) {
        const int bl = lane & 15, ul = lane >> 4;
        const int b = wm * 16 + bl, u = u0 + ul;
        float gi = lds[w][bl][ul * 4 + 0];
        float gf = lds[w][bl][ul * 4 + 1];
        float gg = lds[w][bl][ul * 4 + 2];
        float go = lds[w][bl][ul * 4 + 3];
        const int idx = b * 1024 + u;
        float cp = cs[idx];
        float si = 1.f / (1.f + __expf(-gi));
        float sf = 1.f / (1.f + __expf(-gf));
        float so = 1.f / (1.f + __expf(-go));
        float cn = sf * cp + si * tanhf(gg);
        float hv = so * tanhf(cn);
        cs[idx] = cn;
        ushort hb = f2bf(hv);
        if (layer == 0) {
            hs0[(size_t)(s + 1) * BH + idx] = hb;
            if (s == TT - 1) {
                out[OUT_HL + idx] = hv;
                out[OUT_CL + idx] = cn;
            }
        } else {
            h1[(size_t)((t + 1) & 1) * BH + idx] = hb;
            out[(size_t)t * BH + idx] = hv;
            if (t == TT - 1) {
                out[OUT_HL + BH + idx] = hv;
                out[OUT_CL + BH + idx] = cn;
            }
        }
    }
}

extern "C" void kernel_launch(void* const* d_in, const int* in_sizes, int n_in,
                              void* d_out, int out_size, void* d_ws, size_t ws_size,
                              hipStream_t stream) {
    const float* attn = (const float*)d_in[0];
    const float* x    = (const float*)d_in[1];
    const float* h0   = (const float*)d_in[3];
    const float* c0   = (const float*)d_in[4];
    const float* wah  = (const float*)d_in[5];
    const float* wih  = (const float*)d_in[6];
    const float* whh  = (const float*)d_in[7];
    const float* bah  = (const float*)d_in[8];
    const float* bih  = (const float*)d_in[9];
    const float* bhh  = (const float*)d_in[10];
    float* out = (float*)d_out;

    char* ws = (char*)d_ws;
    // ws layout (bytes):
    ushort* Wt     = (ushort*)(ws);                 // [2][4096][2048] bf16 : 33,554,432
    ushort* xbf    = (ushort*)(ws + 33554432);      // [256][64][1024] bf16 : 33,554,432
    ushort* hs0    = (ushort*)(ws + 67108864);      // [257][64][1024] bf16 : 33,685,504
    ushort* h1     = (ushort*)(ws + 100794368);     // [2][64][1024]  bf16 : 262,144
    float*  constg = (float*)(ws + 101056512);      // [2][64][4096]  f32  : 2,097,152
    float*  cst    = (float*)(ws + 103153664);      // [2][64][1024]  f32  : 524,288
    // total: 103,677,952 B

    hipLaunchKernelGGL(k_prep_wt, dim3(32, 64, 2), dim3(256), 0, stream, wih, whh, Wt);
    hipLaunchKernelGGL(k_cast_x, dim3(16384), dim3(256), 0, stream, x, xbf);
    hipLaunchKernelGGL(k_const, dim3(16, 8, 2), dim3(256), 0, stream, attn, wah, bah, bih, bhh, constg);
    hipLaunchKernelGGL(k_init, dim3(512), dim3(256), 0, stream, h0, c0, hs0, h1, cst);
    for (int s = 0; s <= TT; ++s) {
        hipLaunchKernelGGL(k_step, dim3(256), dim3(512), 0, stream,
                           xbf, hs0, h1, Wt, constg, cst, out, s);
    }
}